// Round 1
// baseline (383.268 us; speedup 1.0000x reference)
//
#include <hip/hip_runtime.h>

// GAT layer, B=8, N=2048, D=128, fp32.
// Kernel A: h = (x*mask) @ W, e_l = h.a_l, e_r = h.a_r  -> workspace
// Kernel B: flash-style online-softmax attention + residual + LayerNorm.

#define BB 8
#define NN 2048
#define DD 128
#define GAT_ALPHA 0.2f
#define GAT_NEG_INF -10000.0f
#define LN_EPS 1e-5f

#define TI 16   // i-rows per block (kernel B)
#define TJ 64   // j-tile (kernel B)
#define PSS 68  // padded stride for ps[TI][PSS]

// ---------------------------------------------------------------------------
// Kernel A: grid = BB * (NN/32), block = 256.
// Each block: 32 rows of h. Threads: r = t>>3 (0..31), c = t&7, o0 = c*16.
// W staged in LDS in two 64-row k-tiles (32 KB), x tile 32x64 padded (8.7 KB).
// ---------------------------------------------------------------------------
__global__ __launch_bounds__(256) void fc_kernel(
    const float* __restrict__ x, const int* __restrict__ mask,
    const float* __restrict__ W, const float* __restrict__ a_l,
    const float* __restrict__ a_r, float* __restrict__ h,
    float* __restrict__ el, float* __restrict__ er)
{
    __shared__ __align__(16) float Ws[64 * DD];   // 32 KB (k-half of W)
    __shared__ __align__(16) float xs[32 * 68];   // padded stride 68

    const int t  = threadIdx.x;
    const int b  = blockIdx.x >> 6;   // / 64
    const int it = blockIdx.x & 63;
    const int i0 = it * 32;

    const int r  = t >> 3;   // 0..31
    const int c  = t & 7;    // 0..7
    const int o0 = c * 16;

    float acc[16];
#pragma unroll
    for (int u = 0; u < 16; ++u) acc[u] = 0.f;

    for (int kt = 0; kt < 2; ++kt) {
        __syncthreads();
        // stage W k-tile: rows kt*64 .. kt*64+63 (8192 floats = 2048 float4)
        const float4* W4  = (const float4*)(W + (size_t)kt * 64 * DD);
        float4*       Ws4 = (float4*)Ws;
#pragma unroll
        for (int i = 0; i < 8; ++i) Ws4[t + 256 * i] = W4[t + 256 * i];
        // stage x tile: rows i0..i0+31, cols kt*64..kt*64+63 (512 float4)
#pragma unroll
        for (int i = 0; i < 2; ++i) {
            int idx = t + 256 * i;          // 0..511
            int row = idx >> 4, c4 = idx & 15;
            float4 v = *(const float4*)(x + ((size_t)(b * NN + i0 + row)) * DD
                                          + kt * 64 + c4 * 4);
            float mm = (float)mask[b * NN + i0 + row];
            v.x *= mm; v.y *= mm; v.z *= mm; v.w *= mm;
            *(float4*)(xs + row * 68 + c4 * 4) = v;
        }
        __syncthreads();

        const float4* Wsr = (const float4*)Ws;
#pragma unroll 4
        for (int k = 0; k < 64; ++k) {
            float xv = xs[r * 68 + k];
#pragma unroll
            for (int u4 = 0; u4 < 4; ++u4) {
                float4 w = Wsr[k * 32 + c * 4 + u4];
                acc[u4 * 4 + 0] += xv * w.x;
                acc[u4 * 4 + 1] += xv * w.y;
                acc[u4 * 4 + 2] += xv * w.z;
                acc[u4 * 4 + 3] += xv * w.w;
            }
        }
    }

    // e_l / e_r partials over this thread's 16 outputs, reduce across 8 lanes
    float sl = 0.f, sr = 0.f;
#pragma unroll
    for (int u = 0; u < 16; ++u) {
        sl += acc[u] * a_l[o0 + u];
        sr += acc[u] * a_r[o0 + u];
    }
#pragma unroll
    for (int off = 4; off; off >>= 1) {
        sl += __shfl_xor(sl, off, 8);
        sr += __shfl_xor(sr, off, 8);
    }

    size_t hbase = ((size_t)(b * NN + i0 + r)) * DD + o0;
#pragma unroll
    for (int u4 = 0; u4 < 4; ++u4)
        *(float4*)(h + hbase + u4 * 4) =
            make_float4(acc[u4 * 4], acc[u4 * 4 + 1], acc[u4 * 4 + 2], acc[u4 * 4 + 3]);

    if (c == 0) {
        el[b * NN + i0 + r] = sl;
        er[b * NN + i0 + r] = sr;
    }
}

// ---------------------------------------------------------------------------
// Kernel B: grid = BB * (NN/TI) = 1024, block = 256 (4 waves).
// Wave w owns output rows i0 + 4w .. 4w+3; lane owns d = {2*lane, 2*lane+1}.
// Score phase: lane (rq=lane>>4, jc=lane&15) computes row rs = 4w+rq,
// j = jc*4..jc*4+3 of the current tile. Online softmax (m,l per row,
// replicated in the row's 16 lanes). p stored to LDS ps[rs][j].
// Accumulate phase: wave reads its 4 rows of ps (broadcast float4) x hs.
// ---------------------------------------------------------------------------
__global__ __launch_bounds__(256) void attn_kernel(
    const float* __restrict__ x, const int* __restrict__ adj,
    const int* __restrict__ mask, const float* __restrict__ h,
    const float* __restrict__ el, const float* __restrict__ er,
    const float* __restrict__ gamma, const float* __restrict__ beta,
    float* __restrict__ outp)
{
    __shared__ __align__(16) float hs[TJ * DD];    // 32 KB
    __shared__ __align__(16) float ps[TI * PSS];   // 4.4 KB
    __shared__ float erj[TJ];
    __shared__ int   mj[TJ];

    const int t    = threadIdx.x;
    const int wv   = t >> 6;        // 0..3
    const int lane = t & 63;
    const int rq   = lane >> 4;     // 0..3
    const int jc   = lane & 15;     // 0..15
    const int b    = blockIdx.x >> 7;    // / (NN/TI)
    const int it   = blockIdx.x & 127;
    const int i0   = it * TI;
    const int rs   = wv * 4 + rq;        // score row 0..15
    const int gi_s = i0 + rs;

    const float el_r = el[b * NN + gi_s];
    const int   mi_s = mask[b * NN + gi_s];
    const int* adj_row = adj + ((size_t)(b * NN + gi_s)) * NN;

    const float g0  = gamma[2 * lane], g1 = gamma[2 * lane + 1];
    const float be0 = beta[2 * lane],  be1 = beta[2 * lane + 1];

    float m_run = -3.0e38f, l_run = 0.f;
    float acc[4][2];
#pragma unroll
    for (int q = 0; q < 4; ++q) { acc[q][0] = 0.f; acc[q][1] = 0.f; }

    for (int jt = 0; jt < NN / TJ; ++jt) {
        __syncthreads();   // protect hs from previous-iteration readers
        // stage h tile: TJ*DD floats = 2048 float4, 8 per thread
        const float4* hsrc = (const float4*)(h + ((size_t)(b * NN + jt * TJ)) * DD);
        float4*       hdst = (float4*)hs;
#pragma unroll
        for (int i = 0; i < 8; ++i) hdst[t + 256 * i] = hsrc[t + 256 * i];
        if (t < TJ) {
            erj[t] = er[b * NN + jt * TJ + t];
            mj[t]  = mask[b * NN + jt * TJ + t];
        }
        __syncthreads();

        // ---- scores for row rs, j = jc*4 .. jc*4+3 ----
        int4 av = *(const int4*)(adj_row + jt * TJ + jc * 4);
        int  avv[4] = {av.x, av.y, av.z, av.w};
        float s[4];
        float tmax = -3.0e38f;
#pragma unroll
        for (int u = 0; u < 4; ++u) {
            int   j  = jc * 4 + u;
            float ev = el_r + erj[j];
            ev = ev > 0.f ? ev : GAT_ALPHA * ev;
            bool allowed = (avv[u] != 0) && (mi_s != 0) && (mj[j] != 0);
            s[u] = allowed ? ev : GAT_NEG_INF;
            tmax = fmaxf(tmax, s[u]);
        }
#pragma unroll
        for (int off = 8; off; off >>= 1) tmax = fmaxf(tmax, __shfl_xor(tmax, off, 16));
        float m_new = fmaxf(m_run, tmax);
        float alpha = __expf(m_run - m_new);
        float psum  = 0.f;
#pragma unroll
        for (int u = 0; u < 4; ++u) {
            float p = __expf(s[u] - m_new);
            ps[rs * PSS + jc * 4 + u] = p;
            psum += p;
        }
#pragma unroll
        for (int off = 8; off; off >>= 1) psum += __shfl_xor(psum, off, 16);
        l_run = l_run * alpha + psum;
        m_run = m_new;

        // rescale accumulators (alpha for row 4w+q lives in lane q*16 of wave)
#pragma unroll
        for (int q = 0; q < 4; ++q) {
            float aq = __shfl(alpha, q * 16, 64);
            acc[q][0] *= aq; acc[q][1] *= aq;
        }

        // ---- accumulate: acc[q][*] += sum_j p[4w+q][j] * hs[j][d] ----
        // ps rows 4w..4w+3 were written by this same wave -> no barrier needed.
#pragma unroll 4
        for (int j4 = 0; j4 < TJ; j4 += 4) {
            float4 p0 = *(const float4*)(ps + (wv * 4 + 0) * PSS + j4);
            float4 p1 = *(const float4*)(ps + (wv * 4 + 1) * PSS + j4);
            float4 p2 = *(const float4*)(ps + (wv * 4 + 2) * PSS + j4);
            float4 p3 = *(const float4*)(ps + (wv * 4 + 3) * PSS + j4);
#pragma unroll
            for (int u = 0; u < 4; ++u) {
                float2 hv = *(const float2*)(hs + (j4 + u) * DD + 2 * lane);
                float pv0 = (&p0.x)[u], pv1 = (&p1.x)[u];
                float pv2 = (&p2.x)[u], pv3 = (&p3.x)[u];
                acc[0][0] += pv0 * hv.x; acc[0][1] += pv0 * hv.y;
                acc[1][0] += pv1 * hv.x; acc[1][1] += pv1 * hv.y;
                acc[2][0] += pv2 * hv.x; acc[2][1] += pv2 * hv.y;
                acc[3][0] += pv3 * hv.x; acc[3][1] += pv3 * hv.y;
            }
        }
    }

    // ---- epilogue: softmax normalize, residual, node mask, LayerNorm ----
#pragma unroll
    for (int q = 0; q < 4; ++q) {
        int   gi  = i0 + wv * 4 + q;
        float lq  = __shfl(l_run, q * 16, 64);
        float inv = 1.0f / lq;
        float mq  = (float)mask[b * NN + gi];
        float2 xv = *(const float2*)(x + ((size_t)(b * NN + gi)) * DD + 2 * lane);
        float v0 = (acc[q][0] * inv + xv.x) * mq;
        float v1 = (acc[q][1] * inv + xv.y) * mq;

        float s1 = v0 + v1, s2 = v0 * v0 + v1 * v1;
#pragma unroll
        for (int off = 32; off; off >>= 1) {
            s1 += __shfl_xor(s1, off, 64);
            s2 += __shfl_xor(s2, off, 64);
        }
        float mu  = s1 * (1.0f / DD);
        float var = s2 * (1.0f / DD) - mu * mu;
        float rsd = rsqrtf(var + LN_EPS);
        float o0 = (v0 - mu) * rsd * g0 + be0;
        float o1 = (v1 - mu) * rsd * g1 + be1;
        *(float2*)(outp + ((size_t)(b * NN + gi)) * DD + 2 * lane) =
            make_float2(o0, o1);
    }
}

// ---------------------------------------------------------------------------
extern "C" void kernel_launch(void* const* d_in, const int* in_sizes, int n_in,
                              void* d_out, int out_size, void* d_ws, size_t ws_size,
                              hipStream_t stream) {
    const float* x     = (const float*)d_in[0];
    const int*   adj   = (const int*)d_in[1];
    const int*   maskp = (const int*)d_in[2];
    const float* W     = (const float*)d_in[3];
    const float* a_l   = (const float*)d_in[4];
    const float* a_r   = (const float*)d_in[5];
    const float* gamma = (const float*)d_in[6];
    const float* beta  = (const float*)d_in[7];
    float*       outp  = (float*)d_out;

    // workspace: h [B*N*D] fp32, e_l [B*N], e_r [B*N]  (~8.5 MB)
    float* h  = (float*)d_ws;
    float* el = h + (size_t)BB * NN * DD;
    float* er = el + (size_t)BB * NN;

    fc_kernel<<<BB * (NN / 32), 256, 0, stream>>>(x, maskp, W, a_l, a_r, h, el, er);
    attn_kernel<<<BB * (NN / TI), 256, 0, stream>>>(x, adj, maskp, h, el, er,
                                                    gamma, beta, outp);
}

// Round 2
// 272.626 us; speedup vs baseline: 1.4058x; 1.4058x over previous
//
#include <hip/hip_runtime.h>
#include <stdint.h>

// GAT layer, B=8, N=2048, D=128, fp32 in/out.
// Kernel A (fc): h = (x*mask)@W -> hT bf16 [B][D][N] (transposed), e_l, e_r.
// Kernel B (attn): wave-self-contained flash attention, MFMA bf16 PV,
//                  no LDS, no barriers in the K-loop. + residual + LayerNorm.

#define BB 8
#define NN 2048
#define DD 128
#define GAT_NEG_INF -10000.0f
#define LN_EPS 1e-5f

typedef __attribute__((ext_vector_type(8))) short short8;
typedef __attribute__((ext_vector_type(4))) float f32x4;

__device__ __forceinline__ unsigned pk_bf16(float a, float b) {
    // RTN-even fp32->bf16 pack (inputs finite)
    unsigned ua = __float_as_uint(a); ua += 0x7FFFu + ((ua >> 16) & 1u);
    unsigned ub = __float_as_uint(b); ub += 0x7FFFu + ((ub >> 16) & 1u);
    return (ua >> 16) | (ub & 0xFFFF0000u);
}

// ---------------------------------------------------------------------------
// Kernel A: grid = BB*(NN/32) = 512, block = 256.
// 32 rows of h per block; thread (r=t>>3, c=t&7) owns row r, cols c*16..+15.
// Epilogue stages the 128x32 transposed tile through LDS and stores bf16 hT.
// ---------------------------------------------------------------------------
__global__ __launch_bounds__(256) void fc_kernel(
    const float* __restrict__ x, const int* __restrict__ mask,
    const float* __restrict__ W, const float* __restrict__ a_l,
    const float* __restrict__ a_r, unsigned short* __restrict__ hT,
    float* __restrict__ el, float* __restrict__ er)
{
    __shared__ __align__(16) float Ws[64 * DD];   // 32 KB; reused as hTs[128][33]
    __shared__ __align__(16) float xs[32 * 68];

    const int t  = threadIdx.x;
    const int b  = blockIdx.x >> 6;
    const int it = blockIdx.x & 63;
    const int i0 = it * 32;

    const int r  = t >> 3;   // 0..31
    const int c  = t & 7;    // 0..7
    const int o0 = c * 16;

    float acc[16];
#pragma unroll
    for (int u = 0; u < 16; ++u) acc[u] = 0.f;

    for (int kt = 0; kt < 2; ++kt) {
        __syncthreads();
        const float4* W4  = (const float4*)(W + (size_t)kt * 64 * DD);
        float4*       Ws4 = (float4*)Ws;
#pragma unroll
        for (int i = 0; i < 8; ++i) Ws4[t + 256 * i] = W4[t + 256 * i];
#pragma unroll
        for (int i = 0; i < 2; ++i) {
            int idx = t + 256 * i;
            int row = idx >> 4, c4 = idx & 15;
            float4 v = *(const float4*)(x + ((size_t)(b * NN + i0 + row)) * DD
                                          + kt * 64 + c4 * 4);
            float mm = (float)mask[b * NN + i0 + row];
            v.x *= mm; v.y *= mm; v.z *= mm; v.w *= mm;
            *(float4*)(xs + row * 68 + c4 * 4) = v;
        }
        __syncthreads();

        const float4* Wsr = (const float4*)Ws;
#pragma unroll 4
        for (int k = 0; k < 64; ++k) {
            float xv = xs[r * 68 + k];
#pragma unroll
            for (int u4 = 0; u4 < 4; ++u4) {
                float4 w = Wsr[k * 32 + c * 4 + u4];
                acc[u4 * 4 + 0] += xv * w.x;
                acc[u4 * 4 + 1] += xv * w.y;
                acc[u4 * 4 + 2] += xv * w.z;
                acc[u4 * 4 + 3] += xv * w.w;
            }
        }
    }

    // e_l / e_r partials, reduce across the 8 col-group lanes
    float sl = 0.f, sr = 0.f;
#pragma unroll
    for (int u = 0; u < 16; ++u) {
        sl += acc[u] * a_l[o0 + u];
        sr += acc[u] * a_r[o0 + u];
    }
#pragma unroll
    for (int off = 4; off; off >>= 1) {
        sl += __shfl_xor(sl, off, 8);
        sr += __shfl_xor(sr, off, 8);
    }
    if (c == 0) {
        el[b * NN + i0 + r] = sl;
        er[b * NN + i0 + r] = sr;
    }

    // ---- transpose tile through LDS, store bf16 hT[b][d][i] ----
    __syncthreads();                  // all waves done reading Ws
    float* hTs = Ws;                  // [128][33] fp32
#pragma unroll
    for (int u = 0; u < 16; ++u) hTs[(o0 + u) * 33 + r] = acc[u];
    __syncthreads();

    {
        int d = t >> 1, half = t & 1;
        const float* src = hTs + d * 33 + half * 16;
        unsigned pk8[8];
#pragma unroll
        for (int k = 0; k < 8; ++k) pk8[k] = pk_bf16(src[2 * k], src[2 * k + 1]);
        unsigned short* dst = hT + ((size_t)(b * DD + d)) * NN + i0 + half * 16;
        *(uint4*)dst       = make_uint4(pk8[0], pk8[1], pk8[2], pk8[3]);
        *(uint4*)(dst + 8) = make_uint4(pk8[4], pk8[5], pk8[6], pk8[7]);
    }
}

// ---------------------------------------------------------------------------
// Kernel B: grid = BB*(NN/16) = 1024 blocks, block = 64 (1 wave, 16 i-rows).
// Lane: row = lane&15 (score/A row), grp = lane>>4 (k-group).
// A-frag: P[m=lane&15][k=grp*8+u]  (computed in-register, bf16 RTN).
// B-frag: H[k][n] with n=lane&15: 8 contiguous j from hT[b][n0+n][.] (global).
// C/D:    col=lane&15, row=grp*4+reg.
// Online softmax state m,l per row, replicated in the row's 4 lanes.
// ---------------------------------------------------------------------------
__global__ __launch_bounds__(64) void attn_kernel(
    const float* __restrict__ x, const int* __restrict__ adj,
    const int* __restrict__ mask, const unsigned short* __restrict__ hT,
    const float* __restrict__ el, const float* __restrict__ er,
    const float* __restrict__ gamma, const float* __restrict__ beta,
    float* __restrict__ outp)
{
    const int lane = threadIdx.x;
    const int row  = lane & 15;
    const int grp  = lane >> 4;
    const int b    = blockIdx.x >> 7;
    const int it   = blockIdx.x & 127;
    const int i0   = it * 16;
    const int gi   = i0 + row;

    const float el_r = el[b * NN + gi];
    const int   mi   = mask[b * NN + gi];
    const int*  adj_row = adj + ((size_t)(b * NN + gi)) * NN;
    const float* er_b = er + b * NN;
    const int*   mk_b = mask + b * NN;
    const unsigned short* hT_b = hT + (size_t)b * DD * NN;

    f32x4 acc[8];
#pragma unroll
    for (int nb = 0; nb < 8; ++nb) acc[nb] = (f32x4)0.f;
    float m_run = -3.0e38f, l_run = 0.f;

    // tile-meta prefetch registers (adj, er, mask-j for the 16 j's this lane owns)
    int4 pa0, pa1, pa2, pa3;
    float4 pe0, pe1, pe2, pe3;
    int4 pq0, pq1, pq2, pq3;

    auto load_meta = [&](int jt) {
        const int jb = jt * 64 + grp * 8;
        pa0 = *(const int4*)(adj_row + jb);
        pa1 = *(const int4*)(adj_row + jb + 4);
        pa2 = *(const int4*)(adj_row + jb + 32);
        pa3 = *(const int4*)(adj_row + jb + 36);
        pe0 = *(const float4*)(er_b + jb);
        pe1 = *(const float4*)(er_b + jb + 4);
        pe2 = *(const float4*)(er_b + jb + 32);
        pe3 = *(const float4*)(er_b + jb + 36);
        pq0 = *(const int4*)(mk_b + jb);
        pq1 = *(const int4*)(mk_b + jb + 4);
        pq2 = *(const int4*)(mk_b + jb + 32);
        pq3 = *(const int4*)(mk_b + jb + 36);
    };
    load_meta(0);

    union BU { int4 q; short8 v; };
    union AU { unsigned u[4]; short8 v; };

#pragma unroll 1
    for (int jt = 0; jt < NN / 64; ++jt) {
        // current tile meta
        int4 a0 = pa0, a1 = pa1, a2 = pa2, a3 = pa3;
        float4 e0 = pe0, e1 = pe1, e2 = pe2, e3 = pe3;
        int4 q0 = pq0, q1 = pq1, q2 = pq2, q3 = pq3;
        // prefetch next tile meta (clamped re-load on last iter)
        load_meta(jt < NN / 64 - 1 ? jt + 1 : jt);

        // B-fragment loads for this tile (16 x 16B from global hT, L2-hot)
        BU bf[16];
        {
            const int jb = jt * 64 + grp * 8;
#pragma unroll
            for (int s = 0; s < 2; ++s)
#pragma unroll
                for (int nb = 0; nb < 8; ++nb)
                    bf[s * 8 + nb].q = *(const int4*)(hT_b
                        + (size_t)(nb * 16 + row) * NN + jb + s * 32);
        }

        // ---- scores for the 16 j's this lane owns ----
        int   av[16] = {a0.x,a0.y,a0.z,a0.w, a1.x,a1.y,a1.z,a1.w,
                        a2.x,a2.y,a2.z,a2.w, a3.x,a3.y,a3.z,a3.w};
        int   qv[16] = {q0.x,q0.y,q0.z,q0.w, q1.x,q1.y,q1.z,q1.w,
                        q2.x,q2.y,q2.z,q2.w, q3.x,q3.y,q3.z,q3.w};
        float ev[16] = {e0.x,e0.y,e0.z,e0.w, e1.x,e1.y,e1.z,e1.w,
                        e2.x,e2.y,e2.z,e2.w, e3.x,e3.y,e3.z,e3.w};
        float ss[16];
        float tmax = -3.0e38f;
#pragma unroll
        for (int u = 0; u < 16; ++u) {
            float e = el_r + ev[u];
            e = fmaxf(e, 0.2f * e);                 // LeakyReLU
            bool ok = (av[u] & qv[u] & mi) != 0;    // adj,mask in {0,1}
            ss[u] = ok ? e : GAT_NEG_INF;
            tmax = fmaxf(tmax, ss[u]);
        }
        tmax = fmaxf(tmax, __shfl_xor(tmax, 16, 64));
        tmax = fmaxf(tmax, __shfl_xor(tmax, 32, 64));
        float m_new = fmaxf(m_run, tmax);
        float al    = __expf(m_run - m_new);
        float p[16];
        float psum = 0.f;
#pragma unroll
        for (int u = 0; u < 16; ++u) {
            p[u] = __expf(ss[u] - m_new);
            psum += p[u];
        }
        psum += __shfl_xor(psum, 16, 64);
        psum += __shfl_xor(psum, 32, 64);
        l_run = l_run * al + psum;
        m_run = m_new;

        // rescale accumulators: C row of element reg is grp*4+reg
        float alr[4];
#pragma unroll
        for (int reg = 0; reg < 4; ++reg) alr[reg] = __shfl(al, grp * 4 + reg, 64);
#pragma unroll
        for (int nb = 0; nb < 8; ++nb) {
            acc[nb][0] *= alr[0]; acc[nb][1] *= alr[1];
            acc[nb][2] *= alr[2]; acc[nb][3] *= alr[3];
        }

        // pack A-fragments (bf16 RTN), k-local order = register element order
        AU A0, A1;
#pragma unroll
        for (int k = 0; k < 4; ++k) {
            A0.u[k] = pk_bf16(p[2 * k],     p[2 * k + 1]);
            A1.u[k] = pk_bf16(p[8 + 2 * k], p[8 + 2 * k + 1]);
        }

        // ---- 16 MFMAs: acc[nb] += P(16x32) @ H(32x16) per kstep ----
#pragma unroll
        for (int nb = 0; nb < 8; ++nb)
            acc[nb] = __builtin_amdgcn_mfma_f32_16x16x32_bf16(A0.v, bf[nb].v, acc[nb], 0, 0, 0);
#pragma unroll
        for (int nb = 0; nb < 8; ++nb)
            acc[nb] = __builtin_amdgcn_mfma_f32_16x16x32_bf16(A1.v, bf[8 + nb].v, acc[nb], 0, 0, 0);
    }

    // ---- epilogue: normalize, residual, node mask, LayerNorm ----
    float inv[4], mq[4];
#pragma unroll
    for (int reg = 0; reg < 4; ++reg) {
        float lq = __shfl(l_run, grp * 4 + reg, 64);
        inv[reg] = 1.0f / lq;
        mq[reg]  = (float)mk_b[i0 + grp * 4 + reg];
    }

    float v[8][4];
    float s1[4] = {0.f, 0.f, 0.f, 0.f}, s2[4] = {0.f, 0.f, 0.f, 0.f};
#pragma unroll
    for (int nb = 0; nb < 8; ++nb)
#pragma unroll
        for (int reg = 0; reg < 4; ++reg) {
            float xv = x[((size_t)(b * NN + i0 + grp * 4 + reg)) * DD + nb * 16 + row];
            float tv = (acc[nb][reg] * inv[reg] + xv) * mq[reg];
            v[nb][reg] = tv;
            s1[reg] += tv;
            s2[reg] += tv * tv;
        }
#pragma unroll
    for (int off = 1; off < 16; off <<= 1)
#pragma unroll
        for (int reg = 0; reg < 4; ++reg) {
            s1[reg] += __shfl_xor(s1[reg], off, 64);
            s2[reg] += __shfl_xor(s2[reg], off, 64);
        }

    float mu[4], rsd[4];
#pragma unroll
    for (int reg = 0; reg < 4; ++reg) {
        mu[reg] = s1[reg] * (1.0f / DD);
        float var = s2[reg] * (1.0f / DD) - mu[reg] * mu[reg];
        rsd[reg] = rsqrtf(var + LN_EPS);
    }
#pragma unroll
    for (int nb = 0; nb < 8; ++nb) {
        float g  = gamma[nb * 16 + row];
        float be = beta[nb * 16 + row];
#pragma unroll
        for (int reg = 0; reg < 4; ++reg) {
            float o = (v[nb][reg] - mu[reg]) * rsd[reg] * g + be;
            outp[((size_t)(b * NN + i0 + grp * 4 + reg)) * DD + nb * 16 + row] = o;
        }
    }
}

// ---------------------------------------------------------------------------
extern "C" void kernel_launch(void* const* d_in, const int* in_sizes, int n_in,
                              void* d_out, int out_size, void* d_ws, size_t ws_size,
                              hipStream_t stream) {
    const float* x     = (const float*)d_in[0];
    const int*   adj   = (const int*)d_in[1];
    const int*   maskp = (const int*)d_in[2];
    const float* W     = (const float*)d_in[3];
    const float* a_l   = (const float*)d_in[4];
    const float* a_r   = (const float*)d_in[5];
    const float* gamma = (const float*)d_in[6];
    const float* beta  = (const float*)d_in[7];
    float*       outp  = (float*)d_out;

    // workspace: hT bf16 [B*D*N] (4 MB), e_l, e_r fp32 [B*N]
    unsigned short* hT = (unsigned short*)d_ws;
    float* el = (float*)(hT + (size_t)BB * DD * NN);
    float* er = el + (size_t)BB * NN;

    fc_kernel<<<BB * (NN / 32), 256, 0, stream>>>(x, maskp, W, a_l, a_r, hT, el, er);
    attn_kernel<<<BB * (NN / 16), 64, 0, stream>>>(x, adj, maskp, hT, el, er,
                                                   gamma, beta, outp);
}